// Round 5
// baseline (181.201 us; speedup 1.0000x reference)
//
#include <hip/hip_runtime.h>
#include <math.h>

// Problem constants (from reference setup_inputs)
constexpr int kB  = 32;
constexpr int kS  = 4096;
constexpr int kH  = 1024;
constexpr int kNC = 128;          // S-chunks per batch
constexpr int kCH = kS / kNC;     // 32 rows per chunk
constexpr int WPB = 2;            // waves per block (128 threads)
constexpr int NP  = kCH / 2;      // 16 row-pairs per chunk
constexpr int NBUF = 3;           // pair-buffers per wave (2 pairs in flight + 1 computing)

// async global->LDS, 16B per lane (64 lanes -> 1KB per instruction).
// LDS dest is wave-uniform base + lane*16 (HW adds the lane offset).
#define GLOAD_LDS16(gp, lp)                                                        \
  __builtin_amdgcn_global_load_lds(                                               \
      (const __attribute__((address_space(1))) void*)(gp),                        \
      (__attribute__((address_space(3))) void*)(lp), 16, 0, 0)

// Stage one row-PAIR (2048 floats) into LDS: 8 x 1KB DMA loads.
__device__ __forceinline__ void stage_pair(const float* __restrict__ g,
                                           float* l, int lane) {
  #pragma unroll
  for (int j = 0; j < 8; ++j)
    GLOAD_LDS16(g + j * 256 + 4 * lane, l + j * 256);
}

// acc4 = acc4*sc + p0*w04 + p1*w14
#define PAIR4(acc4, w04, w14) \
  acc4.x = fmaf(p1, w14.x, fmaf(p0, w04.x, acc4.x * sc)); \
  acc4.y = fmaf(p1, w14.y, fmaf(p0, w04.y, acc4.y * sc)); \
  acc4.z = fmaf(p1, w14.z, fmaf(p0, w04.z, acc4.z * sc)); \
  acc4.w = fmaf(p1, w14.w, fmaf(p0, w04.w, acc4.w * sc));

// ---------------------------------------------------------------------------
// Pass 1: one wave per (batch, chunk). Context rows stream through THREE
// per-wave private LDS pair-buffers via global_load_lds: two pairs always in
// flight (16 KB/wave) while one is computed; explicit vmcnt(16) gating.
// No __syncthreads (buffers are wave-private). 48 KB LDS/block -> 3 blocks/CU.
// ---------------------------------------------------------------------------
__global__ __launch_bounds__(128) void attn_pass1(
    const float* __restrict__ q,      // [B, H]
    const float* __restrict__ ctx,    // [B, S, H]
    float* __restrict__ scores,       // [B, S]   raw logits
    float* __restrict__ pm,           // [B*NC]
    float* __restrict__ pl,           // [B*NC]
    float* __restrict__ pacc)         // [B*NC, H]
{
  // per wave: 3 buffers x 2048 floats = 24 KB; 2 waves = 48 KB
  __shared__ __align__(16) float lds[WPB * NBUF * 2048];

  const int lane = threadIdx.x & 63;
  const int wid  = threadIdx.x >> 6;
  const int wave = blockIdx.x * WPB + wid;   // 0 .. B*NC-1
  const int b    = wave / kNC;
  const int c    = wave % kNC;

  float* wbuf = &lds[wid * NBUF * 2048];

  const float4* qp = reinterpret_cast<const float4*>(q + (size_t)b * kH) + lane;
  const float4 Qa = qp[0], Qb = qp[64], Qc = qp[128], Qd = qp[192];

  const float* cbase = ctx + ((size_t)b * kS + (size_t)c * kCH) * kH;

  float m = -3.0e38f, l = 0.0f;
  float4 aa = make_float4(0.f,0.f,0.f,0.f), ab = aa, ac = aa, ad = aa;
  float myscore = 0.0f;

  auto compute_pair = [&](int t, const float* buf) {
    const float4* p0 = reinterpret_cast<const float4*>(buf) + lane;
    const float4* p1 = p0 + 256;   // second row of the pair

    const float4 w0a = p0[0], w0b = p0[64], w0c = p0[128], w0d = p0[192];
    const float4 w1a = p1[0], w1b = p1[64], w1c = p1[128], w1d = p1[192];

    float d0, d1;
    d0  = w0a.x*Qa.x + w0a.y*Qa.y + w0a.z*Qa.z + w0a.w*Qa.w;
    d0 += w0b.x*Qb.x + w0b.y*Qb.y + w0b.z*Qb.z + w0b.w*Qb.w;
    d0 += w0c.x*Qc.x + w0c.y*Qc.y + w0c.z*Qc.z + w0c.w*Qc.w;
    d0 += w0d.x*Qd.x + w0d.y*Qd.y + w0d.z*Qd.z + w0d.w*Qd.w;
    d1  = w1a.x*Qa.x + w1a.y*Qa.y + w1a.z*Qa.z + w1a.w*Qa.w;
    d1 += w1b.x*Qb.x + w1b.y*Qb.y + w1b.z*Qb.z + w1b.w*Qb.w;
    d1 += w1c.x*Qc.x + w1c.y*Qc.y + w1c.z*Qc.z + w1c.w*Qc.w;
    d1 += w1d.x*Qd.x + w1d.y*Qd.y + w1d.z*Qd.z + w1d.w*Qd.w;

    // two interleaved butterfly chains
    #pragma unroll
    for (int off = 32; off >= 1; off >>= 1) {
      d0 += __shfl_xor(d0, off, 64);
      d1 += __shfl_xor(d1, off, 64);
    }

    if (lane == 2 * t)     myscore = d0;
    if (lane == 2 * t + 1) myscore = d1;

    // branchless online-softmax pair update
    const float nm = fmaxf(m, fmaxf(d0, d1));
    const float sc = __expf(m - nm);          // first pair: exp(-inf) == 0
    const float p0s = __expf(d0 - nm);
    const float p1s = __expf(d1 - nm);
    m = nm;
    l = fmaf(l, sc, p0s + p1s);
    { const float p0 = p0s, p1 = p1s;
      PAIR4(aa, w0a, w1a); PAIR4(ab, w0b, w1b);
      PAIR4(ac, w0c, w1c); PAIR4(ad, w0d, w1d); }
  };

  // prologue: pairs 0,1 in flight (16 loads)
  stage_pair(cbase + 0 * 2048, wbuf + 0 * 2048, lane);
  stage_pair(cbase + 1 * 2048, wbuf + 1 * 2048, lane);

  #pragma unroll
  for (int t = 0; t < NP - 2; ++t) {
    // keep two pairs in flight: stage pair t+2 into buffer (t+2)%3
    stage_pair(cbase + (size_t)(t + 2) * 2048, wbuf + ((t + 2) % NBUF) * 2048, lane);
    // wait until only the 16 in-flight remain -> pair t has landed
    asm volatile("s_waitcnt vmcnt(16)" ::: "memory");
    compute_pair(t, wbuf + (t % NBUF) * 2048);
  }
  asm volatile("s_waitcnt vmcnt(8)" ::: "memory");
  compute_pair(NP - 2, wbuf + ((NP - 2) % NBUF) * 2048);
  asm volatile("s_waitcnt vmcnt(0)" ::: "memory");
  compute_pair(NP - 1, wbuf + ((NP - 1) % NBUF) * 2048);

  // epilogue: coalesced stores
  if (lane < kCH) scores[(size_t)b * kS + (size_t)c * kCH + lane] = myscore;
  if (lane == 0) { pm[wave] = m; pl[wave] = l; }
  float4* pap = reinterpret_cast<float4*>(pacc + (size_t)wave * kH) + lane;
  pap[0] = aa; pap[64] = ab; pap[128] = ac; pap[192] = ad;
}

// ---------------------------------------------------------------------------
// Stats kernel: one block per batch. Reduces the 128 chunk partials to
// (m_g, inv), and writes wgl[i] = exp(pm_i - m_g) * inv (inv folded in).
// ---------------------------------------------------------------------------
__global__ __launch_bounds__(128) void attn_stats(
    const float* __restrict__ pm,
    const float* __restrict__ pl,
    float* __restrict__ wgl,          // [B*NC]
    float2* __restrict__ stats)       // [B] (m_g, inv)
{
  const int b = blockIdx.x;
  const int t = threadIdx.x;
  __shared__ float red[128];

  const float mi = pm[b * kNC + t];
  red[t] = mi;
  __syncthreads();
  #pragma unroll
  for (int o = 64; o >= 1; o >>= 1) {
    if (t < o) red[t] = fmaxf(red[t], red[t + o]);
    __syncthreads();
  }
  const float m_g = red[0];
  __syncthreads();

  const float wi = __expf(mi - m_g);
  red[t] = pl[b * kNC + t] * wi;
  __syncthreads();
  #pragma unroll
  for (int o = 64; o >= 1; o >>= 1) {
    if (t < o) red[t] += red[t + o];
    __syncthreads();
  }
  const float inv = 1.0f / red[0];

  wgl[b * kNC + t] = wi * inv;
  if (t == 0) stats[b] = make_float2(m_g, inv);
}

// ---------------------------------------------------------------------------
// Combine kernel: grid (B, 9). by=0..7: combine one 128-wide h slice of the
// acc partials with precomputed wgl (inv folded), write out = tanh(s).
// by=8: normalize raw logits into attn using (m_g, inv).
// d_out layout: [out (B*H floats)] ++ [attn (B*S floats)]
// ---------------------------------------------------------------------------
__global__ __launch_bounds__(256) void attn_combine(
    const float* __restrict__ scores,
    const float* __restrict__ wgl,
    const float2* __restrict__ stats,
    const float* __restrict__ pacc,
    float* __restrict__ out)
{
  const int b  = blockIdx.x;
  const int by = blockIdx.y;
  const int t  = threadIdx.x;

  if (by < 8) {
    __shared__ float wsh[kNC];
    __shared__ float4 sh4[8][32];
    if (t < kNC) wsh[t] = wgl[b * kNC + t];
    __syncthreads();

    const int h4     = t & 31;   // float4 index within the 128-wide slice
    const int stripe = t >> 5;   // 8 i-stripes
    const float4* base =
        reinterpret_cast<const float4*>(pacc + ((size_t)(b * kNC + stripe)) * kH + by * 128) + h4;
    const size_t istep = (size_t)8 * (kH / 4);  // i += 8, in float4 units

    float4 s = make_float4(0.f, 0.f, 0.f, 0.f);
    #pragma unroll 16
    for (int k = 0; k < 16; ++k) {
      const float w = wsh[stripe + 8 * k];
      const float4 v = base[(size_t)k * istep];
      s.x = fmaf(w, v.x, s.x); s.y = fmaf(w, v.y, s.y);
      s.z = fmaf(w, v.z, s.z); s.w = fmaf(w, v.w, s.w);
    }
    sh4[stripe][h4] = s;
    __syncthreads();

    if (t < 32) {
      float4 r = sh4[0][t];
      #pragma unroll
      for (int i = 1; i < 8; ++i) {
        const float4 v = sh4[i][t];
        r.x += v.x; r.y += v.y; r.z += v.z; r.w += v.w;
      }
      r.x = tanhf(r.x); r.y = tanhf(r.y);
      r.z = tanhf(r.z); r.w = tanhf(r.w);
      reinterpret_cast<float4*>(out + (size_t)b * kH + by * 128)[t] = r;
    }
  } else {
    const float2 st = stats[b];
    const float m_g = st.x, inv = st.y;
    const float4* sb = reinterpret_cast<const float4*>(scores + (size_t)b * kS);
    float4* abuf = reinterpret_cast<float4*>(out + (size_t)kB * kH + (size_t)b * kS);
    #pragma unroll
    for (int k = 0; k < kS / 4 / 256; ++k) {
      const int i = k * 256 + t;
      float4 v = sb[i];
      v.x = __expf(v.x - m_g) * inv; v.y = __expf(v.y - m_g) * inv;
      v.z = __expf(v.z - m_g) * inv; v.w = __expf(v.w - m_g) * inv;
      abuf[i] = v;
    }
  }
}

extern "C" void kernel_launch(void* const* d_in, const int* in_sizes, int n_in,
                              void* d_out, int out_size, void* d_ws, size_t ws_size,
                              hipStream_t stream) {
  const float* q   = (const float*)d_in[0];   // output: (B,1,H) fp32 — the query
  const float* ctx = (const float*)d_in[1];   // context: (B,S,H) fp32
  float* out = (float*)d_out;
  float* ws  = (float*)d_ws;

  // workspace (floats): scores[B*S] | pm[B*NC] | pl[B*NC] | wgl[B*NC] | stats[2B] | pacc[B*NC*H]
  float* scores = ws;
  float* pm     = scores + (size_t)kB * kS;
  float* pl     = pm + kB * kNC;
  float* wgl    = pl + kB * kNC;
  float* statsf = wgl + kB * kNC;
  float* pacc   = statsf + 2 * kB + 32;   // keep 16B alignment

  attn_pass1<<<dim3(kB * kNC / WPB), 128, 0, stream>>>(q, ctx, scores, pm, pl, pacc);
  attn_stats<<<dim3(kB), 128, 0, stream>>>(pm, pl, wgl, (float2*)statsf);
  attn_combine<<<dim3(kB, 9), 256, 0, stream>>>(scores, wgl, (float2*)statsf, pacc, out);
}

// Round 6
// 131.985 us; speedup vs baseline: 1.3729x; 1.3729x over previous
//
#include <hip/hip_runtime.h>
#include <math.h>

// Problem constants (from reference setup_inputs)
constexpr int kB  = 32;
constexpr int kS  = 4096;
constexpr int kH  = 1024;
constexpr int kNC = 128;          // S-chunks per batch
constexpr int kCH = kS / kNC;     // 32 rows per chunk
constexpr int WPB = 4;            // waves per block (256 threads)
constexpr int NBUF = 3;           // row-buffers per wave (2 rows in flight + 1 computing)

// async global->LDS, 16B per lane (64 lanes -> 1KB per instruction).
// LDS dest is wave-uniform base + lane*16 (HW adds the lane offset).
#define GLOAD_LDS16(gp, lp)                                                        \
  __builtin_amdgcn_global_load_lds(                                               \
      (const __attribute__((address_space(1))) void*)(gp),                        \
      (__attribute__((address_space(3))) void*)(lp), 16, 0, 0)

// Stage one context row (1024 floats) into LDS: 4 x 1KB DMA loads.
__device__ __forceinline__ void stage_row(const float* __restrict__ g,
                                          float* l, int lane) {
  #pragma unroll
  for (int j = 0; j < 4; ++j)
    GLOAD_LDS16(g + j * 256 + 4 * lane, l + j * 256);
}

// acc4 = acc4*sc + p*w4
#define ROW4(acc4, w4) \
  acc4.x = fmaf(p, w4.x, acc4.x * sc); \
  acc4.y = fmaf(p, w4.y, acc4.y * sc); \
  acc4.z = fmaf(p, w4.z, acc4.z * sc); \
  acc4.w = fmaf(p, w4.w, acc4.w * sc);

// ---------------------------------------------------------------------------
// Pass 1: one wave per (batch, chunk). Context rows stream through THREE
// per-wave private 4KB LDS row-buffers (rotating pointers) via
// global_load_lds: two rows always in flight (8 KB/wave) while one computes;
// vmcnt(8) gating. 48 KB LDS / 256-thr block -> 3 blocks/CU = 12 waves/CU
// (R4 had 8; R5's regression was 6 — this probes the occupancy axis).
// No __syncthreads (buffers are wave-private).
// ---------------------------------------------------------------------------
__global__ __launch_bounds__(256) void attn_pass1(
    const float* __restrict__ q,      // [B, H]
    const float* __restrict__ ctx,    // [B, S, H]
    float* __restrict__ scores,       // [B, S]   raw logits
    float* __restrict__ pm,           // [B*NC]
    float* __restrict__ pl,           // [B*NC]
    float* __restrict__ pacc)         // [B*NC, H]
{
  // per wave: 3 buffers x 1024 floats = 12 KB; 4 waves = 48 KB
  __shared__ __align__(16) float lds[WPB * NBUF * 1024];

  const int lane = threadIdx.x & 63;
  const int wid  = threadIdx.x >> 6;
  const int wave = blockIdx.x * WPB + wid;   // 0 .. B*NC-1
  const int b    = wave / kNC;
  const int c    = wave % kNC;

  float* bA = &lds[wid * NBUF * 1024];
  float* bB = bA + 1024;
  float* bC = bA + 2048;

  const float4* qp = reinterpret_cast<const float4*>(q + (size_t)b * kH) + lane;
  const float4 Qa = qp[0], Qb = qp[64], Qc = qp[128], Qd = qp[192];

  const float* cbase = ctx + ((size_t)b * kS + (size_t)c * kCH) * kH;

  float m = -3.0e38f, l = 0.0f;
  float4 aa = make_float4(0.f,0.f,0.f,0.f), ab = aa, ac = aa, ad = aa;
  float myscore = 0.0f;

  auto compute_row = [&](int t, const float* buf) {
    const float4* pr = reinterpret_cast<const float4*>(buf) + lane;
    const float4 wa = pr[0], wb = pr[64], wc = pr[128], wd = pr[192];

    float d;
    d  = wa.x*Qa.x + wa.y*Qa.y + wa.z*Qa.z + wa.w*Qa.w;
    d += wb.x*Qb.x + wb.y*Qb.y + wb.z*Qb.z + wb.w*Qb.w;
    d += wc.x*Qc.x + wc.y*Qc.y + wc.z*Qc.z + wc.w*Qc.w;
    d += wd.x*Qd.x + wd.y*Qd.y + wd.z*Qd.z + wd.w*Qd.w;

    // wave-64 butterfly reduce -> full dot in every lane
    #pragma unroll
    for (int off = 32; off >= 1; off >>= 1) d += __shfl_xor(d, off, 64);

    if (lane == t) myscore = d;

    // online-softmax row update (first row: exp(-inf) == 0)
    const float nm = fmaxf(m, d);
    const float sc = __expf(m - nm);
    const float p  = __expf(d - nm);
    m = nm;
    l = fmaf(l, sc, p);
    ROW4(aa, wa); ROW4(ab, wb); ROW4(ac, wc); ROW4(ad, wd);
  };

  // prologue: rows 0,1 in flight (8 loads)
  stage_row(cbase + 0 * 1024, bA, lane);
  stage_row(cbase + 1 * 1024, bB, lane);

  for (int t = 0; t < kCH - 2; ++t) {
    // keep two rows in flight: stage row t+2 into the free buffer
    stage_row(cbase + (size_t)(t + 2) * 1024, bC, lane);
    // wait until only the 8 in-flight remain -> row t has landed
    asm volatile("s_waitcnt vmcnt(8)" ::: "memory");
    compute_row(t, bA);
    float* tmp = bA; bA = bB; bB = bC; bC = tmp;   // rotate
  }
  asm volatile("s_waitcnt vmcnt(4)" ::: "memory");
  compute_row(kCH - 2, bA);
  asm volatile("s_waitcnt vmcnt(0)" ::: "memory");
  compute_row(kCH - 1, bB);

  // epilogue: coalesced stores
  if (lane < kCH) scores[(size_t)b * kS + (size_t)c * kCH + lane] = myscore;
  if (lane == 0) { pm[wave] = m; pl[wave] = l; }
  float4* pap = reinterpret_cast<float4*>(pacc + (size_t)wave * kH) + lane;
  pap[0] = aa; pap[64] = ab; pap[128] = ac; pap[192] = ad;
}

// ---------------------------------------------------------------------------
// Stats kernel: one block per batch. Reduces the 128 chunk partials to
// (m_g, inv), and writes wgl[i] = exp(pm_i - m_g) * inv (inv folded in).
// ---------------------------------------------------------------------------
__global__ __launch_bounds__(128) void attn_stats(
    const float* __restrict__ pm,
    const float* __restrict__ pl,
    float* __restrict__ wgl,          // [B*NC]
    float2* __restrict__ stats)       // [B] (m_g, inv)
{
  const int b = blockIdx.x;
  const int t = threadIdx.x;
  __shared__ float red[128];

  const float mi = pm[b * kNC + t];
  red[t] = mi;
  __syncthreads();
  #pragma unroll
  for (int o = 64; o >= 1; o >>= 1) {
    if (t < o) red[t] = fmaxf(red[t], red[t + o]);
    __syncthreads();
  }
  const float m_g = red[0];
  __syncthreads();

  const float wi = __expf(mi - m_g);
  red[t] = pl[b * kNC + t] * wi;
  __syncthreads();
  #pragma unroll
  for (int o = 64; o >= 1; o >>= 1) {
    if (t < o) red[t] += red[t + o];
    __syncthreads();
  }
  const float inv = 1.0f / red[0];

  wgl[b * kNC + t] = wi * inv;
  if (t == 0) stats[b] = make_float2(m_g, inv);
}

// ---------------------------------------------------------------------------
// Combine kernel: grid (B, 9). by=0..7: combine one 128-wide h slice of the
// acc partials with precomputed wgl (inv folded), write out = tanh(s).
// by=8: normalize raw logits into attn using (m_g, inv).
// d_out layout: [out (B*H floats)] ++ [attn (B*S floats)]
// ---------------------------------------------------------------------------
__global__ __launch_bounds__(256) void attn_combine(
    const float* __restrict__ scores,
    const float* __restrict__ wgl,
    const float2* __restrict__ stats,
    const float* __restrict__ pacc,
    float* __restrict__ out)
{
  const int b  = blockIdx.x;
  const int by = blockIdx.y;
  const int t  = threadIdx.x;

  if (by < 8) {
    __shared__ float wsh[kNC];
    __shared__ float4 sh4[8][32];
    if (t < kNC) wsh[t] = wgl[b * kNC + t];
    __syncthreads();

    const int h4     = t & 31;   // float4 index within the 128-wide slice
    const int stripe = t >> 5;   // 8 i-stripes
    const float4* base =
        reinterpret_cast<const float4*>(pacc + ((size_t)(b * kNC + stripe)) * kH + by * 128) + h4;
    const size_t istep = (size_t)8 * (kH / 4);  // i += 8, in float4 units

    float4 s = make_float4(0.f, 0.f, 0.f, 0.f);
    #pragma unroll 16
    for (int k = 0; k < 16; ++k) {
      const float w = wsh[stripe + 8 * k];
      const float4 v = base[(size_t)k * istep];
      s.x = fmaf(w, v.x, s.x); s.y = fmaf(w, v.y, s.y);
      s.z = fmaf(w, v.z, s.z); s.w = fmaf(w, v.w, s.w);
    }
    sh4[stripe][h4] = s;
    __syncthreads();

    if (t < 32) {
      float4 r = sh4[0][t];
      #pragma unroll
      for (int i = 1; i < 8; ++i) {
        const float4 v = sh4[i][t];
        r.x += v.x; r.y += v.y; r.z += v.z; r.w += v.w;
      }
      r.x = tanhf(r.x); r.y = tanhf(r.y);
      r.z = tanhf(r.z); r.w = tanhf(r.w);
      reinterpret_cast<float4*>(out + (size_t)b * kH + by * 128)[t] = r;
    }
  } else {
    const float2 st = stats[b];
    const float m_g = st.x, inv = st.y;
    const float4* sb = reinterpret_cast<const float4*>(scores + (size_t)b * kS);
    float4* abuf = reinterpret_cast<float4*>(out + (size_t)kB * kH + (size_t)b * kS);
    #pragma unroll
    for (int k = 0; k < kS / 4 / 256; ++k) {
      const int i = k * 256 + t;
      float4 v = sb[i];
      v.x = __expf(v.x - m_g) * inv; v.y = __expf(v.y - m_g) * inv;
      v.z = __expf(v.z - m_g) * inv; v.w = __expf(v.w - m_g) * inv;
      abuf[i] = v;
    }
  }
}

extern "C" void kernel_launch(void* const* d_in, const int* in_sizes, int n_in,
                              void* d_out, int out_size, void* d_ws, size_t ws_size,
                              hipStream_t stream) {
  const float* q   = (const float*)d_in[0];   // output: (B,1,H) fp32 — the query
  const float* ctx = (const float*)d_in[1];   // context: (B,S,H) fp32
  float* out = (float*)d_out;
  float* ws  = (float*)d_ws;

  // workspace (floats): scores[B*S] | pm[B*NC] | pl[B*NC] | wgl[B*NC] | stats[2B] | pacc[B*NC*H]
  float* scores = ws;
  float* pm     = scores + (size_t)kB * kS;
  float* pl     = pm + kB * kNC;
  float* wgl    = pl + kB * kNC;
  float* statsf = wgl + kB * kNC;
  float* pacc   = statsf + 2 * kB + 32;   // keep 16B alignment

  attn_pass1<<<dim3(kB * kNC / WPB), 256, 0, stream>>>(q, ctx, scores, pm, pl, pacc);
  attn_stats<<<dim3(kB), 128, 0, stream>>>(pm, pl, wgl, (float2*)statsf);
  attn_combine<<<dim3(kB, 9), 256, 0, stream>>>(scores, wgl, (float2*)statsf, pacc, out);
}

// Round 7
// 110.468 us; speedup vs baseline: 1.6403x; 1.1948x over previous
//
#include <hip/hip_runtime.h>
#include <math.h>

// Problem constants (from reference setup_inputs)
constexpr int kB  = 32;
constexpr int kS  = 4096;
constexpr int kH  = 1024;
constexpr int kNC = 64;           // S-chunks per batch (64 rows each)
constexpr int kCH = kS / kNC;     // 64 rows per chunk
constexpr int WPB = 4;            // waves per block (256 threads)
constexpr int NP  = kCH / 2;      // 32 row-pairs per chunk

// async global->LDS, 16B per lane (64 lanes -> 1KB per instruction).
// LDS dest is wave-uniform base + lane*16 (HW adds the lane offset).
#define GLOAD_LDS16(gp, lp)                                                        \
  __builtin_amdgcn_global_load_lds(                                               \
      (const __attribute__((address_space(1))) void*)(gp),                        \
      (__attribute__((address_space(3))) void*)(lp), 16, 0, 0)

// Stage one 1024-float context row into LDS (4 x 1KB quarters).
__device__ __forceinline__ void stage_row(const float* __restrict__ g,
                                          float* l, int lane) {
  #pragma unroll
  for (int j = 0; j < 4; ++j)
    GLOAD_LDS16(g + j * 256 + 4 * lane, l + j * 256);
}

// acc4 = acc4*sc + p0*w04 + p1*w14
#define PAIR4(acc4, w04, w14) \
  acc4.x = fmaf(p1, w14.x, fmaf(p0, w04.x, acc4.x * sc)); \
  acc4.y = fmaf(p1, w14.y, fmaf(p0, w04.y, acc4.y * sc)); \
  acc4.z = fmaf(p1, w14.z, fmaf(p0, w04.z, acc4.z * sc)); \
  acc4.w = fmaf(p1, w14.w, fmaf(p0, w04.w, acc4.w * sc));

// ---------------------------------------------------------------------------
// Pass 1: one wave per (batch, chunk of 64 rows). R4's proven schedule:
// double-buffered pair staging via global_load_lds (8KB in flight/wave),
// vmcnt(8) gating, pair-granularity compute with two interleaved butterfly
// chains. 64KB LDS/block -> 2 blocks/CU = 8 waves/CU; 2048 waves total =
// exactly ONE resident generation (no tail).
// ---------------------------------------------------------------------------
__global__ __launch_bounds__(256, 2) void attn_pass1(
    const float* __restrict__ q,      // [B, H]
    const float* __restrict__ ctx,    // [B, S, H]
    float* __restrict__ scores,       // [B, S]   raw logits
    float* __restrict__ pm,           // [B*NC]
    float* __restrict__ pl,           // [B*NC]
    float* __restrict__ pacc)         // [B*NC, H]
{
  // per wave: 2 buffers x 2 rows x 1024 floats = 16 KB; 4 waves = 64 KB
  __shared__ __align__(16) float lds[WPB * 2 * 2048];

  const int lane = threadIdx.x & 63;
  const int wid  = threadIdx.x >> 6;
  const int wave = blockIdx.x * WPB + wid;   // 0 .. B*NC-1
  const int b    = wave / kNC;
  const int c    = wave % kNC;

  float* wbuf = &lds[wid * 4096];

  const float4* qp = reinterpret_cast<const float4*>(q + (size_t)b * kH) + lane;
  const float4 Qa = qp[0], Qb = qp[64], Qc = qp[128], Qd = qp[192];

  const float* cbase = ctx + ((size_t)b * kS + (size_t)c * kCH) * kH;

  float m = -3.0e38f, l = 0.0f;
  float4 aa = make_float4(0.f,0.f,0.f,0.f), ab = aa, ac = aa, ad = aa;
  float myscore = 0.0f;

  auto compute_pair = [&](int t) {
    const float4* p0 = reinterpret_cast<const float4*>(wbuf + (t & 1) * 2048) + lane;
    const float4* p1 = p0 + 256;   // second row of the pair

    const float4 w0a = p0[0], w0b = p0[64], w0c = p0[128], w0d = p0[192];
    const float4 w1a = p1[0], w1b = p1[64], w1c = p1[128], w1d = p1[192];

    float d0, d1;
    d0  = w0a.x*Qa.x + w0a.y*Qa.y + w0a.z*Qa.z + w0a.w*Qa.w;
    d0 += w0b.x*Qb.x + w0b.y*Qb.y + w0b.z*Qb.z + w0b.w*Qb.w;
    d0 += w0c.x*Qc.x + w0c.y*Qc.y + w0c.z*Qc.z + w0c.w*Qc.w;
    d0 += w0d.x*Qd.x + w0d.y*Qd.y + w0d.z*Qd.z + w0d.w*Qd.w;
    d1  = w1a.x*Qa.x + w1a.y*Qa.y + w1a.z*Qa.z + w1a.w*Qa.w;
    d1 += w1b.x*Qb.x + w1b.y*Qb.y + w1b.z*Qb.z + w1b.w*Qb.w;
    d1 += w1c.x*Qc.x + w1c.y*Qc.y + w1c.z*Qc.z + w1c.w*Qc.w;
    d1 += w1d.x*Qd.x + w1d.y*Qd.y + w1d.z*Qd.z + w1d.w*Qd.w;

    // two interleaved butterfly chains
    #pragma unroll
    for (int off = 32; off >= 1; off >>= 1) {
      d0 += __shfl_xor(d0, off, 64);
      d1 += __shfl_xor(d1, off, 64);
    }

    if (lane == 2 * t)     myscore = d0;
    if (lane == 2 * t + 1) myscore = d1;

    // branchless online-softmax pair update
    const float nm = fmaxf(m, fmaxf(d0, d1));
    const float sc = __expf(m - nm);          // first pair: exp(-inf) == 0
    const float p0s = __expf(d0 - nm);
    const float p1s = __expf(d1 - nm);
    m = nm;
    l = fmaf(l, sc, p0s + p1s);
    { const float p0 = p0s, p1 = p1s;
      PAIR4(aa, w0a, w1a); PAIR4(ab, w0b, w1b);
      PAIR4(ac, w0c, w1c); PAIR4(ad, w0d, w1d); }
  };

  // prologue: stage pair 0 into buffer 0 (8 loads in flight)
  stage_row(cbase,        wbuf,        lane);
  stage_row(cbase + 1024, wbuf + 1024, lane);

  for (int t = 0; t < NP - 1; ++t) {
    // issue next pair's 8 DMA loads into the other buffer
    const float* g  = cbase + (size_t)(t + 1) * 2048;
    float*       lb = wbuf + ((t + 1) & 1) * 2048;
    stage_row(g,        lb,        lane);
    stage_row(g + 1024, lb + 1024, lane);
    // wait until only the 8 just-issued remain -> pair t has landed
    asm volatile("s_waitcnt vmcnt(8)" ::: "memory");
    compute_pair(t);
  }
  asm volatile("s_waitcnt vmcnt(0)" ::: "memory");
  compute_pair(NP - 1);

  // epilogue: coalesced stores (kCH == 64 -> every lane stores one logit)
  scores[(size_t)b * kS + (size_t)c * kCH + lane] = myscore;
  if (lane == 0) { pm[wave] = m; pl[wave] = l; }
  float4* pap = reinterpret_cast<float4*>(pacc + (size_t)wave * kH) + lane;
  pap[0] = aa; pap[64] = ab; pap[128] = ac; pap[192] = ad;
}

// ---------------------------------------------------------------------------
// Combine kernel: grid (B, 9). Every block recomputes (m_g, inv) from the 64
// chunk partials (cheap). by=0..7: combine one 128-wide h slice of the acc
// partials, write out = tanh(acc*inv). by=8: normalize logits into attn.
// d_out layout: [out (B*H floats)] ++ [attn (B*S floats)]
// ---------------------------------------------------------------------------
__global__ __launch_bounds__(256) void attn_combine(
    const float* __restrict__ scores,
    const float* __restrict__ pm,
    const float* __restrict__ pl,
    const float* __restrict__ pacc,
    float* __restrict__ out)
{
  const int b  = blockIdx.x;
  const int by = blockIdx.y;
  const int t  = threadIdx.x;

  __shared__ float red[256];
  __shared__ float wgt[kNC];

  // global max over this batch's 64 chunk maxima
  const float mi = (t < kNC) ? pm[b * kNC + t] : -3.0e38f;
  red[t] = mi;
  __syncthreads();
  #pragma unroll
  for (int o = 128; o >= 1; o >>= 1) {
    if (t < o) red[t] = fmaxf(red[t], red[t + o]);
    __syncthreads();
  }
  const float m_g = red[0];
  __syncthreads();

  float li = 0.0f, wi = 0.0f;
  if (t < kNC) {
    wi = __expf(mi - m_g);
    li = pl[b * kNC + t] * wi;
  }
  red[t] = li;
  __syncthreads();
  #pragma unroll
  for (int o = 128; o >= 1; o >>= 1) {
    if (t < o) red[t] += red[t + o];
    __syncthreads();
  }
  const float inv = 1.0f / red[0];
  if (t < kNC) wgt[t] = wi * inv;   // inv folded into combine weights
  __syncthreads();

  if (by < 8) {
    __shared__ float4 sh4[8][32];
    const int h4     = t & 31;   // float4 index within the 128-wide slice
    const int stripe = t >> 5;   // 8 i-stripes
    const float4* base =
        reinterpret_cast<const float4*>(pacc + ((size_t)(b * kNC + stripe)) * kH + by * 128) + h4;
    const size_t istep = (size_t)8 * (kH / 4);  // i += 8, in float4 units

    float4 s = make_float4(0.f, 0.f, 0.f, 0.f);
    #pragma unroll 8
    for (int k = 0; k < kNC / 8; ++k) {
      const float w = wgt[stripe + 8 * k];
      const float4 v = base[(size_t)k * istep];
      s.x = fmaf(w, v.x, s.x); s.y = fmaf(w, v.y, s.y);
      s.z = fmaf(w, v.z, s.z); s.w = fmaf(w, v.w, s.w);
    }
    sh4[stripe][h4] = s;
    __syncthreads();

    if (t < 32) {
      float4 r = sh4[0][t];
      #pragma unroll
      for (int i = 1; i < 8; ++i) {
        const float4 v = sh4[i][t];
        r.x += v.x; r.y += v.y; r.z += v.z; r.w += v.w;
      }
      r.x = tanhf(r.x); r.y = tanhf(r.y);
      r.z = tanhf(r.z); r.w = tanhf(r.w);
      reinterpret_cast<float4*>(out + (size_t)b * kH + by * 128)[t] = r;
    }
  } else {
    const float4* sb = reinterpret_cast<const float4*>(scores + (size_t)b * kS);
    float4* abuf = reinterpret_cast<float4*>(out + (size_t)kB * kH + (size_t)b * kS);
    #pragma unroll
    for (int k = 0; k < kS / 4 / 256; ++k) {
      const int i = k * 256 + t;
      float4 v = sb[i];
      v.x = __expf(v.x - m_g) * inv; v.y = __expf(v.y - m_g) * inv;
      v.z = __expf(v.z - m_g) * inv; v.w = __expf(v.w - m_g) * inv;
      abuf[i] = v;
    }
  }
}

extern "C" void kernel_launch(void* const* d_in, const int* in_sizes, int n_in,
                              void* d_out, int out_size, void* d_ws, size_t ws_size,
                              hipStream_t stream) {
  const float* q   = (const float*)d_in[0];   // output: (B,1,H) fp32 — the query
  const float* ctx = (const float*)d_in[1];   // context: (B,S,H) fp32
  float* out = (float*)d_out;
  float* ws  = (float*)d_ws;

  // workspace (floats): scores[B*S] | pm[B*NC] | pl[B*NC] | pacc[B*NC*H]
  float* scores = ws;
  float* pm     = scores + (size_t)kB * kS;
  float* pl     = pm + kB * kNC;
  float* pacc   = pl + kB * kNC;   // offset 135168 floats -> 16B aligned

  attn_pass1<<<dim3(kB * kNC / WPB), 256, 0, stream>>>(q, ctx, scores, pm, pl, pacc);
  attn_combine<<<dim3(kB, 9), 256, 0, stream>>>(scores, pm, pl, pacc, out);
}

// Round 9
// 104.892 us; speedup vs baseline: 1.7275x; 1.0532x over previous
//
#include <hip/hip_runtime.h>
#include <math.h>

// Problem constants (from reference setup_inputs)
constexpr int kB  = 32;
constexpr int kS  = 4096;
constexpr int kH  = 1024;
constexpr int kNC = 64;           // S-chunks per batch (64 rows each)
constexpr int kCH = kS / kNC;     // 64 rows per chunk
constexpr int WPB = 2;            // waves per block (128 threads)
constexpr int NP  = kCH / 2;      // 32 row-pairs per chunk
constexpr int NSLOT = 5;          // 4KB row-slots per wave

// async global->LDS, 16B per lane (64 lanes -> 1KB per instruction).
// LDS dest is wave-uniform base + lane*16 (HW adds the lane offset).
#define GLOAD_LDS16(gp, lp)                                                        \
  __builtin_amdgcn_global_load_lds(                                               \
      (const __attribute__((address_space(1))) void*)(gp),                        \
      (__attribute__((address_space(3))) void*)(lp), 16, 0, 0)

// Stage one 1024-float context row into LDS (4 x 1KB quarters).
__device__ __forceinline__ void stage_row(const float* __restrict__ g,
                                          float* l, int lane) {
  #pragma unroll
  for (int j = 0; j < 4; ++j)
    GLOAD_LDS16(g + j * 256 + 4 * lane, l + j * 256);
}

// acc4 = acc4*sc + p0*w04 + p1*w14
#define PAIR4(acc4, w04, w14) \
  acc4.x = fmaf(p1, w14.x, fmaf(p0, w04.x, acc4.x * sc)); \
  acc4.y = fmaf(p1, w14.y, fmaf(p0, w04.y, acc4.y * sc)); \
  acc4.z = fmaf(p1, w14.z, fmaf(p0, w04.z, acc4.z * sc)); \
  acc4.w = fmaf(p1, w14.w, fmaf(p0, w04.w, acc4.w * sc));

// ---------------------------------------------------------------------------
// Pass 1: one wave per (batch, chunk of 64 rows). 5-slot row ring, issue
// SPLIT around compute to avoid the R8 slot collision:
//   iter t: stage row 2t+4 (slot (2t+4)%5, disjoint from live slots)
//           vmcnt(12)  -> rows 2t,2t+1 landed (12 loads = 3 rows remain)
//           compute pair t (slots (2t)%5,(2t+1)%5)
//           [fence] stage row 2t+5 (slot (2t)%5 — just consumed)
// Steady in-flight 12-16 loads (12-16KB/wave, ~2x R7) at UNCHANGED 8 waves/CU
// (20KB/wave, 40KB per 128-thr block -> 4 blocks/CU). Slot audit in header.
// ---------------------------------------------------------------------------
__global__ __launch_bounds__(128, 2) void attn_pass1(
    const float* __restrict__ q,      // [B, H]
    const float* __restrict__ ctx,    // [B, S, H]
    float* __restrict__ scores,       // [B, S]   raw logits
    float* __restrict__ pm,           // [B*NC]
    float* __restrict__ pl,           // [B*NC]
    float* __restrict__ pacc)         // [B*NC, H]
{
  // per wave: 5 slots x 1024 floats = 20 KB; 2 waves = 40 KB
  __shared__ __align__(16) float lds[WPB * NSLOT * 1024];

  const int lane = threadIdx.x & 63;
  const int wid  = threadIdx.x >> 6;
  const int wave = blockIdx.x * WPB + wid;   // 0 .. B*NC-1
  const int b    = wave / kNC;
  const int c    = wave % kNC;

  float* wbuf = &lds[wid * NSLOT * 1024];

  const float4* qp = reinterpret_cast<const float4*>(q + (size_t)b * kH) + lane;
  const float4 Qa = qp[0], Qb = qp[64], Qc = qp[128], Qd = qp[192];

  const float* cbase = ctx + ((size_t)b * kS + (size_t)c * kCH) * kH;

  float m = -3.0e38f, l = 0.0f;
  float4 aa = make_float4(0.f,0.f,0.f,0.f), ab = aa, ac = aa, ad = aa;
  float myscore = 0.0f;

  // compute pair t from two row slots
  auto compute_pair = [&](int t, const float* buf0, const float* buf1) {
    const float4* p0 = reinterpret_cast<const float4*>(buf0) + lane;
    const float4* p1 = reinterpret_cast<const float4*>(buf1) + lane;

    const float4 w0a = p0[0], w0b = p0[64], w0c = p0[128], w0d = p0[192];
    const float4 w1a = p1[0], w1b = p1[64], w1c = p1[128], w1d = p1[192];

    float d0, d1;
    d0  = w0a.x*Qa.x + w0a.y*Qa.y + w0a.z*Qa.z + w0a.w*Qa.w;
    d0 += w0b.x*Qb.x + w0b.y*Qb.y + w0b.z*Qb.z + w0b.w*Qb.w;
    d0 += w0c.x*Qc.x + w0c.y*Qc.y + w0c.z*Qc.z + w0c.w*Qc.w;
    d0 += w0d.x*Qd.x + w0d.y*Qd.y + w0d.z*Qd.z + w0d.w*Qd.w;
    d1  = w1a.x*Qa.x + w1a.y*Qa.y + w1a.z*Qa.z + w1a.w*Qa.w;
    d1 += w1b.x*Qb.x + w1b.y*Qb.y + w1b.z*Qb.z + w1b.w*Qb.w;
    d1 += w1c.x*Qc.x + w1c.y*Qc.y + w1c.z*Qc.z + w1c.w*Qc.w;
    d1 += w1d.x*Qd.x + w1d.y*Qd.y + w1d.z*Qd.z + w1d.w*Qd.w;

    // two interleaved butterfly chains
    #pragma unroll
    for (int off = 32; off >= 1; off >>= 1) {
      d0 += __shfl_xor(d0, off, 64);
      d1 += __shfl_xor(d1, off, 64);
    }

    if (lane == 2 * t)     myscore = d0;
    if (lane == 2 * t + 1) myscore = d1;

    // branchless online-softmax pair update
    const float nm = fmaxf(m, fmaxf(d0, d1));
    const float sc = __expf(m - nm);          // first pair: exp(-inf) == 0
    const float p0s = __expf(d0 - nm);
    const float p1s = __expf(d1 - nm);
    m = nm;
    l = fmaf(l, sc, p0s + p1s);
    { const float p0 = p0s, p1 = p1s;
      PAIR4(aa, w0a, w1a); PAIR4(ab, w0b, w1b);
      PAIR4(ac, w0c, w1c); PAIR4(ad, w0d, w1d); }
  };

  // prologue: rows 0..3 into slots 0..3 (16 loads in flight)
  stage_row(cbase + 0 * 1024, wbuf + 0 * 1024, lane);
  stage_row(cbase + 1 * 1024, wbuf + 1 * 1024, lane);
  stage_row(cbase + 2 * 1024, wbuf + 2 * 1024, lane);
  stage_row(cbase + 3 * 1024, wbuf + 3 * 1024, lane);

  for (int t = 0; t < NP - 2; ++t) {
    // early issue: row 2t+4 -> slot (2t+4)%5 (disjoint from all live slots)
    const int r0 = 2 * t + 4;
    stage_row(cbase + (size_t)r0 * 1024, wbuf + (r0 % NSLOT) * 1024, lane);
    // 12 loads (rows 2t+2,2t+3,2t+4) remain -> rows 2t,2t+1 have landed
    asm volatile("s_waitcnt vmcnt(12)" ::: "memory");
    compute_pair(t, wbuf + ((2 * t) % NSLOT) * 1024,
                    wbuf + ((2 * t + 1) % NSLOT) * 1024);
    // late issue: row 2t+5 -> slot (2t)%5, which compute_pair(t) just
    // consumed. Fence keeps this issue AFTER the pair's LDS reads.
    asm volatile("" ::: "memory");
    const int r1 = 2 * t + 5;
    stage_row(cbase + (size_t)r1 * 1024, wbuf + (r1 % NSLOT) * 1024, lane);
  }
  // drain: pair NP-2 = rows 60,61 (slots 0,1); rows 62,63 still in flight
  asm volatile("s_waitcnt vmcnt(8)" ::: "memory");
  compute_pair(NP - 2, wbuf + ((2 * (NP - 2)) % NSLOT) * 1024,
                       wbuf + ((2 * (NP - 2) + 1) % NSLOT) * 1024);
  asm volatile("s_waitcnt vmcnt(0)" ::: "memory");
  compute_pair(NP - 1, wbuf + ((2 * (NP - 1)) % NSLOT) * 1024,
                       wbuf + ((2 * (NP - 1) + 1) % NSLOT) * 1024);

  // epilogue: coalesced stores (kCH == 64 -> every lane stores one logit)
  scores[(size_t)b * kS + (size_t)c * kCH + lane] = myscore;
  if (lane == 0) { pm[wave] = m; pl[wave] = l; }
  float4* pap = reinterpret_cast<float4*>(pacc + (size_t)wave * kH) + lane;
  pap[0] = aa; pap[64] = ab; pap[128] = ac; pap[192] = ad;
}

// ---------------------------------------------------------------------------
// Combine kernel: grid (B, 9). Wave 0 of each block recomputes (m_g, inv)
// from the 64 chunk partials via shuffle reduction (1 barrier).
// by=0..7: combine one 128-wide h slice of acc partials, out = tanh(acc*inv).
// by=8: normalize logits into attn.
// d_out layout: [out (B*H floats)] ++ [attn (B*S floats)]
// ---------------------------------------------------------------------------
__global__ __launch_bounds__(256) void attn_combine(
    const float* __restrict__ scores,
    const float* __restrict__ pm,
    const float* __restrict__ pl,
    const float* __restrict__ pacc,
    float* __restrict__ out)
{
  const int b  = blockIdx.x;
  const int by = blockIdx.y;
  const int t  = threadIdx.x;

  __shared__ float wgt[kNC];
  __shared__ float2 stat_sh;

  if (t < 64) {   // wave 0 computes stats (kNC == 64: one lane per chunk)
    const float mi = pm[b * kNC + t];
    float mg = mi;
    #pragma unroll
    for (int off = 32; off >= 1; off >>= 1) mg = fmaxf(mg, __shfl_xor(mg, off, 64));
    const float wi = __expf(mi - mg);
    float li = pl[b * kNC + t] * wi;
    #pragma unroll
    for (int off = 32; off >= 1; off >>= 1) li += __shfl_xor(li, off, 64);
    const float inv = 1.0f / li;
    wgt[t] = wi * inv;                     // inv folded into combine weights
    if (t == 0) stat_sh = make_float2(mg, inv);
  }
  __syncthreads();

  if (by < 8) {
    __shared__ float4 sh4[8][32];
    const int h4     = t & 31;   // float4 index within the 128-wide slice
    const int stripe = t >> 5;   // 8 i-stripes
    const float4* base =
        reinterpret_cast<const float4*>(pacc + ((size_t)(b * kNC + stripe)) * kH + by * 128) + h4;
    const size_t istep = (size_t)8 * (kH / 4);  // i += 8, in float4 units

    float4 s = make_float4(0.f, 0.f, 0.f, 0.f);
    #pragma unroll 8
    for (int k = 0; k < kNC / 8; ++k) {
      const float w = wgt[stripe + 8 * k];
      const float4 v = base[(size_t)k * istep];
      s.x = fmaf(w, v.x, s.x); s.y = fmaf(w, v.y, s.y);
      s.z = fmaf(w, v.z, s.z); s.w = fmaf(w, v.w, s.w);
    }
    sh4[stripe][h4] = s;
    __syncthreads();

    if (t < 32) {
      float4 r = sh4[0][t];
      #pragma unroll
      for (int i = 1; i < 8; ++i) {
        const float4 v = sh4[i][t];
        r.x += v.x; r.y += v.y; r.z += v.z; r.w += v.w;
      }
      r.x = tanhf(r.x); r.y = tanhf(r.y);
      r.z = tanhf(r.z); r.w = tanhf(r.w);
      reinterpret_cast<float4*>(out + (size_t)b * kH + by * 128)[t] = r;
    }
  } else {
    const float m_g = stat_sh.x, inv = stat_sh.y;
    const float4* sb = reinterpret_cast<const float4*>(scores + (size_t)b * kS);
    float4* abuf = reinterpret_cast<float4*>(out + (size_t)kB * kH + (size_t)b * kS);
    #pragma unroll
    for (int k = 0; k < kS / 4 / 256; ++k) {
      const int i = k * 256 + t;
      float4 v = sb[i];
      v.x = __expf(v.x - m_g) * inv; v.y = __expf(v.y - m_g) * inv;
      v.z = __expf(v.z - m_g) * inv; v.w = __expf(v.w - m_g) * inv;
      abuf[i] = v;
    }
  }
}

extern "C" void kernel_launch(void* const* d_in, const int* in_sizes, int n_in,
                              void* d_out, int out_size, void* d_ws, size_t ws_size,
                              hipStream_t stream) {
  const float* q   = (const float*)d_in[0];   // output: (B,1,H) fp32 — the query
  const float* ctx = (const float*)d_in[1];   // context: (B,S,H) fp32
  float* out = (float*)d_out;
  float* ws  = (float*)d_ws;

  // workspace (floats): scores[B*S] | pm[B*NC] | pl[B*NC] | pacc[B*NC*H]
  float* scores = ws;
  float* pm     = scores + (size_t)kB * kS;
  float* pl     = pm + kB * kNC;
  float* pacc   = pl + kB * kNC;   // 16B-aligned offset

  attn_pass1<<<dim3(kB * kNC / WPB), 128, 0, stream>>>(q, ctx, scores, pm, pl, pacc);
  attn_combine<<<dim3(kB, 9), 256, 0, stream>>>(scores, pm, pl, pacc, out);
}

// Round 10
// 93.707 us; speedup vs baseline: 1.9337x; 1.1194x over previous
//
#include <hip/hip_runtime.h>
#include <math.h>

// Problem constants (from reference setup_inputs)
constexpr int kB  = 32;
constexpr int kS  = 4096;
constexpr int kH  = 1024;
constexpr int kNC = 64;           // S-chunks per batch (64 rows each)
constexpr int kCH = kS / kNC;     // 64 rows per chunk
constexpr int WPB = 2;            // waves per block (128 threads)
constexpr int NP  = kCH / 2;      // 32 row-pairs per chunk
constexpr int NSLOT = 5;          // 4KB row-slots per wave

// async global->LDS, 16B per lane (64 lanes -> 1KB per instruction).
// aux=2 sets the NT (non-temporal / SLC) bit: context is streamed once,
// don't allocate in L2. LDS dest is wave-uniform base + lane*16.
#define GLOAD_LDS16_NT(gp, lp)                                                     \
  __builtin_amdgcn_global_load_lds(                                               \
      (const __attribute__((address_space(1))) void*)(gp),                        \
      (__attribute__((address_space(3))) void*)(lp), 16, 0, 2)

// Stage one 1024-float context row into LDS (4 x 1KB quarters), NT policy.
__device__ __forceinline__ void stage_row(const float* __restrict__ g,
                                          float* l, int lane) {
  #pragma unroll
  for (int j = 0; j < 4; ++j)
    GLOAD_LDS16_NT(g + j * 256 + 4 * lane, l + j * 256);
}

// acc4 = acc4*sc + p0*w04 + p1*w14
#define PAIR4(acc4, w04, w14) \
  acc4.x = fmaf(p1, w14.x, fmaf(p0, w04.x, acc4.x * sc)); \
  acc4.y = fmaf(p1, w14.y, fmaf(p0, w04.y, acc4.y * sc)); \
  acc4.z = fmaf(p1, w14.z, fmaf(p0, w04.z, acc4.z * sc)); \
  acc4.w = fmaf(p1, w14.w, fmaf(p0, w04.w, acc4.w * sc));

// One pair's worth of row data in registers.
struct PR { float4 w0a, w0b, w0c, w0d, w1a, w1b, w1c, w1d; };

__device__ __forceinline__ PR load_pair(const float* buf0, const float* buf1,
                                        int lane) {
  const float4* p0 = reinterpret_cast<const float4*>(buf0) + lane;
  const float4* p1 = reinterpret_cast<const float4*>(buf1) + lane;
  PR r;
  r.w0a = p0[0]; r.w0b = p0[64]; r.w0c = p0[128]; r.w0d = p0[192];
  r.w1a = p1[0]; r.w1b = p1[64]; r.w1c = p1[128]; r.w1d = p1[192];
  return r;
}

// ---------------------------------------------------------------------------
// Pass 1: one wave per (batch, chunk of 64 rows). 5-slot row ring, R9's
// split-issue refined: the second row's DMA now issues right after the
// pair's LDS reads COMPLETE (explicit lgkmcnt(0) + sched_barrier makes the
// slot reuse race-free), i.e. BEFORE the ~700-cycle math chain, keeping 16
// loads (16KB/wave) in flight through math. 8 waves/CU (20KB/wave = full
// 160KB LDS). Per-iter slot audit:
//   top:   issue row 2t+4 -> slot (2t+4)%5  (live slots 2t..2t+3 disjoint)
//   vmcnt(12): rows 2t,2t+1 landed
//   ds_read pair t (slots (2t)%5,(2t+1)%5); lgkmcnt(0)
//   issue row 2t+5 -> slot (2t)%5 (reads complete, loads outstanding are
//   rows 2t+2,2t+3,2t+4 -> slots 2,3,4 mod-shifted, disjoint)
//   math pair t
// ---------------------------------------------------------------------------
__global__ __launch_bounds__(128, 2) void attn_pass1(
    const float* __restrict__ q,      // [B, H]
    const float* __restrict__ ctx,    // [B, S, H]
    float* __restrict__ scores,       // [B, S]   raw logits
    float* __restrict__ pm,           // [B*NC]
    float* __restrict__ pl,           // [B*NC]
    float* __restrict__ pacc)         // [B*NC, H]
{
  // per wave: 5 slots x 1024 floats = 20 KB; 2 waves = 40 KB
  __shared__ __align__(16) float lds[WPB * NSLOT * 1024];

  const int lane = threadIdx.x & 63;
  const int wid  = threadIdx.x >> 6;
  const int wave = blockIdx.x * WPB + wid;   // 0 .. B*NC-1
  const int b    = wave / kNC;
  const int c    = wave % kNC;

  float* wbuf = &lds[wid * NSLOT * 1024];

  const float4* qp = reinterpret_cast<const float4*>(q + (size_t)b * kH) + lane;
  const float4 Qa = qp[0], Qb = qp[64], Qc = qp[128], Qd = qp[192];

  const float* cbase = ctx + ((size_t)b * kS + (size_t)c * kCH) * kH;

  float m = -3.0e38f, l = 0.0f;
  float4 aa = make_float4(0.f,0.f,0.f,0.f), ab = aa, ac = aa, ad = aa;
  float myscore = 0.0f;

  auto math_pair = [&](int t, const PR& w) {
    float d0, d1;
    d0  = w.w0a.x*Qa.x + w.w0a.y*Qa.y + w.w0a.z*Qa.z + w.w0a.w*Qa.w;
    d0 += w.w0b.x*Qb.x + w.w0b.y*Qb.y + w.w0b.z*Qb.z + w.w0b.w*Qb.w;
    d0 += w.w0c.x*Qc.x + w.w0c.y*Qc.y + w.w0c.z*Qc.z + w.w0c.w*Qc.w;
    d0 += w.w0d.x*Qd.x + w.w0d.y*Qd.y + w.w0d.z*Qd.z + w.w0d.w*Qd.w;
    d1  = w.w1a.x*Qa.x + w.w1a.y*Qa.y + w.w1a.z*Qa.z + w.w1a.w*Qa.w;
    d1 += w.w1b.x*Qb.x + w.w1b.y*Qb.y + w.w1b.z*Qb.z + w.w1b.w*Qb.w;
    d1 += w.w1c.x*Qc.x + w.w1c.y*Qc.y + w.w1c.z*Qc.z + w.w1c.w*Qc.w;
    d1 += w.w1d.x*Qd.x + w.w1d.y*Qd.y + w.w1d.z*Qd.z + w.w1d.w*Qd.w;

    // two interleaved butterfly chains
    #pragma unroll
    for (int off = 32; off >= 1; off >>= 1) {
      d0 += __shfl_xor(d0, off, 64);
      d1 += __shfl_xor(d1, off, 64);
    }

    if (lane == 2 * t)     myscore = d0;
    if (lane == 2 * t + 1) myscore = d1;

    // branchless online-softmax pair update
    const float nm = fmaxf(m, fmaxf(d0, d1));
    const float sc = __expf(m - nm);          // first pair: exp(-inf) == 0
    const float p0s = __expf(d0 - nm);
    const float p1s = __expf(d1 - nm);
    m = nm;
    l = fmaf(l, sc, p0s + p1s);
    { const float p0 = p0s, p1 = p1s;
      PAIR4(aa, w.w0a, w.w1a); PAIR4(ab, w.w0b, w.w1b);
      PAIR4(ac, w.w0c, w.w1c); PAIR4(ad, w.w0d, w.w1d); }
  };

  // prologue: rows 0..3 into slots 0..3 (16 loads in flight)
  stage_row(cbase + 0 * 1024, wbuf + 0 * 1024, lane);
  stage_row(cbase + 1 * 1024, wbuf + 1 * 1024, lane);
  stage_row(cbase + 2 * 1024, wbuf + 2 * 1024, lane);
  stage_row(cbase + 3 * 1024, wbuf + 3 * 1024, lane);

  for (int t = 0; t < NP - 2; ++t) {
    // early issue: row 2t+4 -> slot (2t+4)%5
    const int r0 = 2 * t + 4;
    stage_row(cbase + (size_t)r0 * 1024, wbuf + (r0 % NSLOT) * 1024, lane);
    // rows 2t+2,2t+3,2t+4 (12 loads) remain -> rows 2t,2t+1 have landed
    asm volatile("s_waitcnt vmcnt(12)" ::: "memory");
    const PR w = load_pair(wbuf + ((2 * t) % NSLOT) * 1024,
                           wbuf + ((2 * t + 1) % NSLOT) * 1024, lane);
    // ensure the pair's LDS reads have COMPLETED before reusing slot (2t)%5
    asm volatile("s_waitcnt lgkmcnt(0)" ::: "memory");
    __builtin_amdgcn_sched_barrier(0);
    const int r1 = 2 * t + 5;
    stage_row(cbase + (size_t)r1 * 1024, wbuf + (r1 % NSLOT) * 1024, lane);
    // math runs with 16 loads in flight
    math_pair(t, w);
  }
  // drain: pair NP-2 = rows 60,61 (slots 0,1); rows 62,63 (slots 2,3) in flight
  asm volatile("s_waitcnt vmcnt(8)" ::: "memory");
  {
    const PR w = load_pair(wbuf + ((2 * (NP - 2)) % NSLOT) * 1024,
                           wbuf + ((2 * (NP - 2) + 1) % NSLOT) * 1024, lane);
    math_pair(NP - 2, w);
  }
  asm volatile("s_waitcnt vmcnt(0)" ::: "memory");
  {
    const PR w = load_pair(wbuf + ((2 * (NP - 1)) % NSLOT) * 1024,
                           wbuf + ((2 * (NP - 1) + 1) % NSLOT) * 1024, lane);
    math_pair(NP - 1, w);
  }

  // epilogue: coalesced stores (kCH == 64 -> every lane stores one logit)
  scores[(size_t)b * kS + (size_t)c * kCH + lane] = myscore;
  if (lane == 0) { pm[wave] = m; pl[wave] = l; }
  float4* pap = reinterpret_cast<float4*>(pacc + (size_t)wave * kH) + lane;
  pap[0] = aa; pap[64] = ab; pap[128] = ac; pap[192] = ad;
}

// ---------------------------------------------------------------------------
// Combine kernel: grid (B, 9). Wave 0 of each block recomputes (m_g, inv)
// from the 64 chunk partials via shuffle reduction (1 barrier).
// by=0..7: combine one 128-wide h slice of acc partials, out = tanh(acc*inv).
// by=8: normalize logits into attn.
// d_out layout: [out (B*H floats)] ++ [attn (B*S floats)]
// ---------------------------------------------------------------------------
__global__ __launch_bounds__(256) void attn_combine(
    const float* __restrict__ scores,
    const float* __restrict__ pm,
    const float* __restrict__ pl,
    const float* __restrict__ pacc,
    float* __restrict__ out)
{
  const int b  = blockIdx.x;
  const int by = blockIdx.y;
  const int t  = threadIdx.x;

  __shared__ float wgt[kNC];
  __shared__ float2 stat_sh;

  if (t < 64) {   // wave 0 computes stats (kNC == 64: one lane per chunk)
    const float mi = pm[b * kNC + t];
    float mg = mi;
    #pragma unroll
    for (int off = 32; off >= 1; off >>= 1) mg = fmaxf(mg, __shfl_xor(mg, off, 64));
    const float wi = __expf(mi - mg);
    float li = pl[b * kNC + t] * wi;
    #pragma unroll
    for (int off = 32; off >= 1; off >>= 1) li += __shfl_xor(li, off, 64);
    const float inv = 1.0f / li;
    wgt[t] = wi * inv;                     // inv folded into combine weights
    if (t == 0) stat_sh = make_float2(mg, inv);
  }
  __syncthreads();

  if (by < 8) {
    __shared__ float4 sh4[8][32];
    const int h4     = t & 31;   // float4 index within the 128-wide slice
    const int stripe = t >> 5;   // 8 i-stripes
    const float4* base =
        reinterpret_cast<const float4*>(pacc + ((size_t)(b * kNC + stripe)) * kH + by * 128) + h4;
    const size_t istep = (size_t)8 * (kH / 4);  // i += 8, in float4 units

    float4 s = make_float4(0.f, 0.f, 0.f, 0.f);
    #pragma unroll 8
    for (int k = 0; k < kNC / 8; ++k) {
      const float w = wgt[stripe + 8 * k];
      const float4 v = base[(size_t)k * istep];
      s.x = fmaf(w, v.x, s.x); s.y = fmaf(w, v.y, s.y);
      s.z = fmaf(w, v.z, s.z); s.w = fmaf(w, v.w, s.w);
    }
    sh4[stripe][h4] = s;
    __syncthreads();

    if (t < 32) {
      float4 r = sh4[0][t];
      #pragma unroll
      for (int i = 1; i < 8; ++i) {
        const float4 v = sh4[i][t];
        r.x += v.x; r.y += v.y; r.z += v.z; r.w += v.w;
      }
      r.x = tanhf(r.x); r.y = tanhf(r.y);
      r.z = tanhf(r.z); r.w = tanhf(r.w);
      reinterpret_cast<float4*>(out + (size_t)b * kH + by * 128)[t] = r;
    }
  } else {
    const float m_g = stat_sh.x, inv = stat_sh.y;
    const float4* sb = reinterpret_cast<const float4*>(scores + (size_t)b * kS);
    float4* abuf = reinterpret_cast<float4*>(out + (size_t)kB * kH + (size_t)b * kS);
    #pragma unroll
    for (int k = 0; k < kS / 4 / 256; ++k) {
      const int i = k * 256 + t;
      float4 v = sb[i];
      v.x = __expf(v.x - m_g) * inv; v.y = __expf(v.y - m_g) * inv;
      v.z = __expf(v.z - m_g) * inv; v.w = __expf(v.w - m_g) * inv;
      abuf[i] = v;
    }
  }
}

extern "C" void kernel_launch(void* const* d_in, const int* in_sizes, int n_in,
                              void* d_out, int out_size, void* d_ws, size_t ws_size,
                              hipStream_t stream) {
  const float* q   = (const float*)d_in[0];   // output: (B,1,H) fp32 — the query
  const float* ctx = (const float*)d_in[1];   // context: (B,S,H) fp32
  float* out = (float*)d_out;
  float* ws  = (float*)d_ws;

  // workspace (floats): scores[B*S] | pm[B*NC] | pl[B*NC] | pacc[B*NC*H]
  float* scores = ws;
  float* pm     = scores + (size_t)kB * kS;
  float* pl     = pm + kB * kNC;
  float* pacc   = pl + kB * kNC;   // 16B-aligned offset

  attn_pass1<<<dim3(kB * kNC / WPB), 128, 0, stream>>>(q, ctx, scores, pm, pl, pacc);
  attn_combine<<<dim3(kB, 9), 256, 0, stream>>>(scores, pm, pl, pacc, out);
}